// Round 1
// baseline (126.062 us; speedup 1.0000x reference)
//
#include <hip/hip_runtime.h>
#include <hip/hip_bf16.h>

#define EMBED 512
#define NSEQ 2048
#define NROWS 4096

typedef unsigned short u16;
typedef __bf16 bf16x8 __attribute__((ext_vector_type(8)));
typedef float f32x4 __attribute__((ext_vector_type(4)));
typedef unsigned short ushort8 __attribute__((ext_vector_type(8)));

__device__ __forceinline__ u16 f2bf(float f) {
    unsigned u = __float_as_uint(f);
    unsigned r = (u + 0x7FFFu + ((u >> 16) & 1u)) >> 16;
    return (u16)r;
}
__device__ __forceinline__ float bf2f(u16 v) {
    return __uint_as_float((unsigned)v << 16);
}

#define XELEMS    (NROWS * EMBED)     // 2097152
#define WQKELEMS  (1024 * EMBED)      // 524288

// ---------------------------------------------------------------------------
// prep: blocks 0..255: x -> bf16 (16 rows each) + per-block fp32 column sums
//       blocks 256..511: Wq|Wk -> Wcat bf16.
// xcs_part layout: [batch][dim][128 row-blocks] for vectorized reduce later.
// ---------------------------------------------------------------------------
__global__ __launch_bounds__(256) void prep_kernel(
    const float* __restrict__ x,
    const float* __restrict__ Wq, const float* __restrict__ Wk,
    u16* __restrict__ xb, u16* __restrict__ Wcat,
    float* __restrict__ xcs_part)
{
    __shared__ float cs[4][512];
    const int bid = blockIdx.x, t = threadIdx.x;
    if (bid < 256) {
        const float* src = x + (size_t)bid * 16 * EMBED;
        u16* dst = xb + (size_t)bid * 16 * EMBED;
        const int rl = t >> 6;            // row-in-4 (== wave)
        const int co = (t & 63) * 8;      // col octet
        float s0=0.f,s1=0.f,s2=0.f,s3=0.f,s4=0.f,s5=0.f,s6=0.f,s7=0.f;
#pragma unroll
        for (int i = 0; i < 4; ++i) {
            const size_t off = (size_t)(i * 4 + rl) * EMBED + co;
            float4 a = *(const float4*)(src + off);
            float4 b = *(const float4*)(src + off + 4);
            union { u16 u[8]; uint4 v; } p;
            p.u[0]=f2bf(a.x); p.u[1]=f2bf(a.y); p.u[2]=f2bf(a.z); p.u[3]=f2bf(a.w);
            p.u[4]=f2bf(b.x); p.u[5]=f2bf(b.y); p.u[6]=f2bf(b.z); p.u[7]=f2bf(b.w);
            *(uint4*)(dst + off) = p.v;
            s0+=a.x; s1+=a.y; s2+=a.z; s3+=a.w;
            s4+=b.x; s5+=b.y; s6+=b.z; s7+=b.w;
        }
        f32x4 v0 = {s0,s1,s2,s3}, v1 = {s4,s5,s6,s7};
        *(f32x4*)&cs[rl][co]     = v0;
        *(f32x4*)&cs[rl][co + 4] = v1;
        __syncthreads();
        const int b = bid >> 7, blk = bid & 127;
#pragma unroll
        for (int d = t; d < 512; d += 256) {
            xcs_part[((size_t)b * 512 + d) * 128 + blk] =
                cs[0][d] + cs[1][d] + cs[2][d] + cs[3][d];
        }
    } else {
        const long long e0 = (long long)(bid - 256) * 2048 + (long long)t * 8;
        const int row = (int)(e0 >> 9), col = (int)(e0 & 511);
        const float* src = (row < 512) ? (Wq + (size_t)row * EMBED + col)
                                       : (Wk + (size_t)(row - 512) * EMBED + col);
        float4 a = *(const float4*)(src);
        float4 b = *(const float4*)(src + 4);
        union { u16 u[8]; uint4 v; } p;
        p.u[0]=f2bf(a.x); p.u[1]=f2bf(a.y); p.u[2]=f2bf(a.z); p.u[3]=f2bf(a.w);
        p.u[4]=f2bf(b.x); p.u[5]=f2bf(b.y); p.u[6]=f2bf(b.z); p.u[7]=f2bf(b.w);
        *(uint4*)(Wcat + e0) = p.v;
    }
}

// ---------------------------------------------------------------------------
// Q|K GEMM (blocks 0..511): 128x64 tiles over N=1024 (V projection removed —
// attn only ever needs V rows 0..2 and colsum(V), handled by small blocks).
// Small blocks 512..543: (batch, head, j-half). Reduce xcs partials, compute
// the 4 V-vectors (rows 0..2 + tail), then WT[j][4h+t] directly.
// ---------------------------------------------------------------------------
__global__ __launch_bounds__(256) void gemm_qk_mfma(
    const u16* __restrict__ A, const u16* __restrict__ W,
    const float* __restrict__ bq, const float* __restrict__ bk,
    const float* __restrict__ xcs_part, const float* __restrict__ bv,
    const float* __restrict__ Wv, const float* __restrict__ Wo,
    u16* __restrict__ QKb, float* __restrict__ WT)
{
    __shared__ __align__(16) u16 As[128 * 64];   // 16 KB
    __shared__ __align__(16) u16 Bs[64 * 64];    // 8 KB
    const int t = threadIdx.x;

    if (blockIdx.x >= 512) {
        // ---------------- small epilogue blocks ----------------
        float* xcs  = (float*)As;        // [512]
        float* Vraw = (float*)Bs;        // [4][64]
        float* Vloc = Vraw + 256;        // [4][64]
        const int sid = blockIdx.x - 512;          // 0..31
        const int b = sid >> 4, h = (sid >> 1) & 7, jhalf = sid & 1;

        // 1) xcs[d] = sum over 128 row-block partials (fp32, deterministic)
        {
            const float* p = xcs_part + ((size_t)b * 512 + 2 * t) * 128;
            float a0 = 0.f, a1 = 0.f;
#pragma unroll 4
            for (int i = 0; i < 128; i += 4) {
                f32x4 u0 = *(const f32x4*)(p + i);
                f32x4 u1 = *(const f32x4*)(p + 128 + i);
                a0 += u0[0] + u0[1] + u0[2] + u0[3];
                a1 += u1[0] + u1[1] + u1[2] + u1[3];
            }
            xcs[2 * t] = a0; xcs[2 * t + 1] = a1;
        }
        __syncthreads();

        // 2) raw V dots: wave tt<3 -> x row tt of batch; wave 3 -> colsum row
        const int tt = t >> 6, cl = t & 63;
        const int col = h * 64 + cl;
        const float* wv = Wv + (size_t)col * EMBED;
        float r = 0.f;
        if (tt < 3) {
            const u16* xr = A + ((size_t)b * NSEQ + tt) * EMBED;
#pragma unroll 8
            for (int d = 0; d < EMBED; d += 8) {
                ushort8 xv = *(const ushort8*)(xr + d);
                f32x4 w0 = *(const f32x4*)(wv + d);
                f32x4 w1 = *(const f32x4*)(wv + d + 4);
                r = fmaf(bf2f(xv[0]), w0[0], r);
                r = fmaf(bf2f(xv[1]), w0[1], r);
                r = fmaf(bf2f(xv[2]), w0[2], r);
                r = fmaf(bf2f(xv[3]), w0[3], r);
                r = fmaf(bf2f(xv[4]), w1[0], r);
                r = fmaf(bf2f(xv[5]), w1[1], r);
                r = fmaf(bf2f(xv[6]), w1[2], r);
                r = fmaf(bf2f(xv[7]), w1[3], r);
            }
        } else {
#pragma unroll 8
            for (int d = 0; d < EMBED; d += 4) {
                f32x4 w = *(const f32x4*)(wv + d);
                r = fmaf(xcs[d],     w[0], r);
                r = fmaf(xcs[d + 1], w[1], r);
                r = fmaf(xcs[d + 2], w[2], r);
                r = fmaf(xcs[d + 3], w[3], r);
            }
        }
        Vraw[tt * 64 + cl] = r;
        __syncthreads();
        // biased rows; tail = colsumV - (v0+v1+v2) = r3 - (r0+r1+r2) + 2045*bv
        const float bvc = bv[col];
        if (tt < 3) Vloc[tt * 64 + cl] = r + bvc;
        else        Vloc[192 + cl] = r - (Vraw[cl] + Vraw[64 + cl] + Vraw[128 + cl])
                                       + 2045.f * bvc;
        __syncthreads();

        // 3) WT[b][j][4h+t] = sum_{c in head h} Vloc[t][c] * Wo[j][c]
        const int j = jhalf * 256 + t;
        const float* wo = Wo + (size_t)j * EMBED + h * 64;
        float a0 = 0.f, a1 = 0.f, a2 = 0.f, a3 = 0.f;
#pragma unroll
        for (int c = 0; c < 64; c += 4) {
            f32x4 w = *(const f32x4*)(wo + c);
#pragma unroll
            for (int z = 0; z < 4; ++z) {
                a0 = fmaf(Vloc[c + z],       w[z], a0);
                a1 = fmaf(Vloc[64 + c + z],  w[z], a1);
                a2 = fmaf(Vloc[128 + c + z], w[z], a2);
                a3 = fmaf(Vloc[192 + c + z], w[z], a3);
            }
        }
        float* wt = WT + ((size_t)b * 512 + j) * 32 + h * 4;
        wt[0] = a0; wt[1] = a1; wt[2] = a2; wt[3] = a3;
        return;
    }

    // ---------------- big GEMM blocks (Q|K only) ----------------
    const int m0 = (blockIdx.x & 31) * 128;
    const int n0 = (blockIdx.x >> 5) * 64;             // 0..960
    const int sel = n0 >> 9;                           // 0:Q 1:K
    const float* bias = ((sel == 0) ? bq : bk) + (n0 & 511);

    const int wave = t >> 6, lane = t & 63;
    const int wm   = wave >> 1, wn = wave & 1;
    const int qd   = lane >> 4, lr = lane & 15;

    const int sr8 = lane >> 3;                 // row-in-8 for staging
    const int sg  = (lane & 7) ^ sr8;          // swizzled global granule
    const int soff = sg * 8;                   // global k offset (elems)

    f32x4 acc[4][2] = {};

    const u16* Ag = A + (size_t)m0 * EMBED;
    const u16* Wg = W + (size_t)n0 * EMBED;

    u16* Adst = As + (size_t)(wave * 8) * 64;
    u16* Bdst = Bs + (size_t)(wave * 8) * 64;
    const u16* Asrc = Ag + (size_t)(wave * 8 + sr8) * EMBED + soff;
    const u16* Bsrc = Wg + (size_t)(wave * 8 + sr8) * EMBED + soff;

    for (int kc = 0; kc < EMBED; kc += 64) {
#pragma unroll
        for (int j = 0; j < 4; ++j)
            __builtin_amdgcn_global_load_lds(
                (const __attribute__((address_space(1))) void*)(Asrc + kc + (size_t)j * 32 * EMBED),
                (__attribute__((address_space(3))) void*)(Adst + j * 32 * 64), 16, 0, 0);
#pragma unroll
        for (int j = 0; j < 2; ++j)
            __builtin_amdgcn_global_load_lds(
                (const __attribute__((address_space(1))) void*)(Bsrc + kc + (size_t)j * 32 * EMBED),
                (__attribute__((address_space(3))) void*)(Bdst + j * 32 * 64), 16, 0, 0);
        __syncthreads();

#pragma unroll
        for (int kk = 0; kk < 2; ++kk) {
            const int gr = ((kk * 4 + qd) ^ (lr & 7)) * 8;
            bf16x8 af[4], bfr[2];
#pragma unroll
            for (int i = 0; i < 4; ++i)
                af[i]  = *(const bf16x8*)&As[(wm * 64 + i * 16 + lr) * 64 + gr];
#pragma unroll
            for (int i = 0; i < 2; ++i)
                bfr[i] = *(const bf16x8*)&Bs[(wn * 32 + i * 16 + lr) * 64 + gr];
#pragma unroll
            for (int mi = 0; mi < 4; ++mi)
#pragma unroll
                for (int ni = 0; ni < 2; ++ni)
                    acc[mi][ni] = __builtin_amdgcn_mfma_f32_16x16x32_bf16(
                        af[mi], bfr[ni], acc[mi][ni], 0, 0, 0);
        }
        __syncthreads();
    }

    // C/D layout: col=lane&15, row=(lane>>4)*4+reg
#pragma unroll
    for (int ni = 0; ni < 2; ++ni) {
        const int cl = wn * 32 + ni * 16 + lr;
        const float bb = bias[cl];
#pragma unroll
        for (int mi = 0; mi < 4; ++mi)
#pragma unroll
            for (int e = 0; e < 4; ++e) {
                const int row = m0 + wm * 64 + mi * 16 + qd * 4 + e;
                QKb[(size_t)row * 1024 + n0 + cl] = f2bf(acc[mi][ni][e] + bb);
            }
    }
}

// ---------------------------------------------------------------------------
// Fused attention + K=32 output GEMM. 512 blocks x 8 rows (2 blocks/CU).
// ---------------------------------------------------------------------------
__global__ __launch_bounds__(256) void attn_out_kernel(
    const u16* __restrict__ QKb, const float* __restrict__ WT,
    const float* __restrict__ bo, float* __restrict__ out)
{
    __shared__ float E[8][32];
    const int r0   = blockIdx.x * 8;
    const int b    = r0 >> 11;
    const int wave = threadIdx.x >> 6, lane = threadIdx.x & 63;
    const int d0   = lane * 8;

#pragma unroll
    for (int i = 0; i < 2; ++i) {
        const int rl = wave * 2 + i;
        const int r  = r0 + rl;
        const int sr = r & (NSEQ - 1);
        const u16* Qr = QKb + (size_t)r * 1024 + d0;
        const u16* Kr = QKb + (size_t)r * 1024 + 512 + d0;

        ushort8 qv = *(const ushort8*)Qr;
        ushort8 kv = *(const ushort8*)Kr;
        float q[8], k[8];
#pragma unroll
        for (int z = 0; z < 8; ++z) { q[z] = bf2f(qv[z]); k[z] = bf2f(kv[z]); }

        float s1 = 0.f;
#pragma unroll
        for (int z = 0; z < 8; ++z) s1 = fmaf(q[z], k[z], s1);

        float s0 = 0.f, s2 = 0.f;
        if (sr > 0) {
            ushort8 pv = *(const ushort8*)(Kr - 1024);
#pragma unroll
            for (int z = 0; z < 8; ++z) s0 = fmaf(q[z], bf2f(pv[z]), s0);
        }
        if (sr < NSEQ - 1) {
            ushort8 nv = *(const ushort8*)(Kr + 1024);
#pragma unroll
            for (int z = 0; z < 8; ++z) s2 = fmaf(q[z], bf2f(nv[z]), s2);
        }
#pragma unroll
        for (int off = 1; off <= 4; off <<= 1) {
            s0 += __shfl_xor(s0, off);
            s1 += __shfl_xor(s1, off);
            s2 += __shfl_xor(s2, off);
        }
        const float m  = fmaxf(fmaxf(s0, s1), fmaxf(s2, 0.f));
        const float e0 = __expf(s0 - m);
        const float e1 = __expf(s1 - m);
        const float e2 = __expf(s2 - m);
        const float eb = __expf(-m);
        const float rd = 1.f / (e0 + e1 + e2 + (float)(NSEQ - 3) * eb);
        const int h = lane >> 3, jj = lane & 7;
        const float coef = (jj == 0) ? e0 : (jj == 1) ? e1 : (jj == 2) ? e2 : eb;
        if (jj < 4) E[rl][h * 4 + jj] = coef * rd;
    }
    __syncthreads();

    const int j0 = threadIdx.x * 2;
    const float* WTb = WT + (size_t)b * 512 * 32;
    float w0[32], w1[32];
#pragma unroll
    for (int s = 0; s < 32; ++s) {
        w0[s] = WTb[(size_t)j0 * 32 + s];
        w1[s] = WTb[(size_t)(j0 + 1) * 32 + s];
    }
    const float b0 = bo[j0], b1 = bo[j0 + 1];
#pragma unroll
    for (int rl = 0; rl < 8; ++rl) {
        float a0 = b0, a1 = b1;
#pragma unroll
        for (int s = 0; s < 32; ++s) {
            const float e = E[rl][s];
            a0 = fmaf(e, w0[s], a0);
            a1 = fmaf(e, w1[s], a1);
        }
        *(float2*)(out + (size_t)(r0 + rl) * EMBED + j0) = make_float2(a0, a1);
    }
}

extern "C" void kernel_launch(void* const* d_in, const int* in_sizes, int n_in,
                              void* d_out, int out_size, void* d_ws, size_t ws_size,
                              hipStream_t stream)
{
    const float* x  = (const float*)d_in[0];
    const float* Wq = (const float*)d_in[1];
    const float* bq = (const float*)d_in[2];
    const float* Wk = (const float*)d_in[3];
    const float* bk = (const float*)d_in[4];
    const float* Wv = (const float*)d_in[5];
    const float* bv = (const float*)d_in[6];
    const float* Wo = (const float*)d_in[7];
    const float* bo = (const float*)d_in[8];
    float* out = (float*)d_out;

    u16*   QKb      = (u16*)d_ws;                      // 4096*1024 u16 (Q|K bf16)
    u16*   xb       = QKb + (size_t)NROWS * 1024;      // 4096*512 bf16
    u16*   Wcat     = xb + XELEMS;                     // 1024*512 bf16 (Wq|Wk)
    float* xcs_part = (float*)(Wcat + WQKELEMS);       // 2*512*128 f32
    float* WT       = xcs_part + 2 * 512 * 128;        // 2*512*32 f32

    prep_kernel<<<512, 256, 0, stream>>>(x, Wq, Wk, xb, Wcat, xcs_part);
    gemm_qk_mfma<<<544, 256, 0, stream>>>(xb, Wcat, bq, bk, xcs_part, bv, Wv, Wo,
                                          QKb, WT);
    attn_out_kernel<<<512, 256, 0, stream>>>(QKb, WT, bo, out);
}

// Round 2
// 117.601 us; speedup vs baseline: 1.0719x; 1.0719x over previous
//
#include <hip/hip_runtime.h>
#include <hip/hip_bf16.h>

#define EMBED 512
#define NSEQ 2048
#define NROWS 4096

typedef unsigned short u16;
typedef __bf16 bf16x8 __attribute__((ext_vector_type(8)));
typedef float f32x4 __attribute__((ext_vector_type(4)));
typedef unsigned short ushort8 __attribute__((ext_vector_type(8)));

__device__ __forceinline__ u16 f2bf(float f) {
    unsigned u = __float_as_uint(f);
    unsigned r = (u + 0x7FFFu + ((u >> 16) & 1u)) >> 16;
    return (u16)r;
}
__device__ __forceinline__ float bf2f(u16 v) {
    return __uint_as_float((unsigned)v << 16);
}

#define XELEMS    (NROWS * EMBED)     // 2097152
#define WQKELEMS  (1024 * EMBED)      // 524288

// ---------------------------------------------------------------------------
// prep: blocks 0..255: x -> bf16 (16 rows each) + per-block fp32 column sums
//       blocks 256..511: Wq|Wk -> Wcat bf16.
// xcs_part layout: [batch][blk][dim] — coalesced write here, coalesced
// float2 read in the small reduce blocks.
// ---------------------------------------------------------------------------
__global__ __launch_bounds__(256) void prep_kernel(
    const float* __restrict__ x,
    const float* __restrict__ Wq, const float* __restrict__ Wk,
    u16* __restrict__ xb, u16* __restrict__ Wcat,
    float* __restrict__ xcs_part)
{
    __shared__ float cs[4][512];
    const int bid = blockIdx.x, t = threadIdx.x;
    if (bid < 256) {
        const float* src = x + (size_t)bid * 16 * EMBED;
        u16* dst = xb + (size_t)bid * 16 * EMBED;
        const int rl = t >> 6;            // row-in-4 (== wave)
        const int co = (t & 63) * 8;      // col octet
        float s0=0.f,s1=0.f,s2=0.f,s3=0.f,s4=0.f,s5=0.f,s6=0.f,s7=0.f;
#pragma unroll
        for (int i = 0; i < 4; ++i) {
            const size_t off = (size_t)(i * 4 + rl) * EMBED + co;
            float4 a = *(const float4*)(src + off);
            float4 b = *(const float4*)(src + off + 4);
            union { u16 u[8]; uint4 v; } p;
            p.u[0]=f2bf(a.x); p.u[1]=f2bf(a.y); p.u[2]=f2bf(a.z); p.u[3]=f2bf(a.w);
            p.u[4]=f2bf(b.x); p.u[5]=f2bf(b.y); p.u[6]=f2bf(b.z); p.u[7]=f2bf(b.w);
            *(uint4*)(dst + off) = p.v;
            s0+=a.x; s1+=a.y; s2+=a.z; s3+=a.w;
            s4+=b.x; s5+=b.y; s6+=b.z; s7+=b.w;
        }
        f32x4 v0 = {s0,s1,s2,s3}, v1 = {s4,s5,s6,s7};
        *(f32x4*)&cs[rl][co]     = v0;
        *(f32x4*)&cs[rl][co + 4] = v1;
        __syncthreads();
        const int b = bid >> 7, blk = bid & 127;
#pragma unroll
        for (int d = t; d < 512; d += 256) {
            xcs_part[((size_t)b * 128 + blk) * 512 + d] =
                cs[0][d] + cs[1][d] + cs[2][d] + cs[3][d];
        }
    } else {
        const long long e0 = (long long)(bid - 256) * 2048 + (long long)t * 8;
        const int row = (int)(e0 >> 9), col = (int)(e0 & 511);
        const float* src = (row < 512) ? (Wq + (size_t)row * EMBED + col)
                                       : (Wk + (size_t)(row - 512) * EMBED + col);
        float4 a = *(const float4*)(src);
        float4 b = *(const float4*)(src + 4);
        union { u16 u[8]; uint4 v; } p;
        p.u[0]=f2bf(a.x); p.u[1]=f2bf(a.y); p.u[2]=f2bf(a.z); p.u[3]=f2bf(a.w);
        p.u[4]=f2bf(b.x); p.u[5]=f2bf(b.y); p.u[6]=f2bf(b.z); p.u[7]=f2bf(b.w);
        *(uint4*)(Wcat + e0) = p.v;
    }
}

// ---------------------------------------------------------------------------
// blocks 0..31:  small V/WT epilogue blocks (run FIRST so they overlap the
//                first GEMM round instead of tailing).
// blocks 32..543: Q|K GEMM, 128x64 tiles, BK=64, double-buffered LDS with a
//                2-phase pipeline: stage(k+1) issued BEFORE compute(k), one
//                barrier per K-step (loads drain at the barrier's vmcnt(0)).
// ---------------------------------------------------------------------------
__global__ __launch_bounds__(256) void gemm_qk_mfma(
    const u16* __restrict__ A, const u16* __restrict__ W,
    const float* __restrict__ bq, const float* __restrict__ bk,
    const float* __restrict__ xcs_part, const float* __restrict__ bv,
    const float* __restrict__ Wv, const float* __restrict__ Wo,
    u16* __restrict__ QKb, float* __restrict__ WT)
{
    __shared__ __align__(16) u16 As[2 * 128 * 64];   // 32 KB
    __shared__ __align__(16) u16 Bs[2 * 64 * 64];    // 16 KB
    const int t = threadIdx.x;

    if (blockIdx.x < 32) {
        // ---------------- small epilogue blocks ----------------
        float* xcs  = (float*)As;        // [512]
        float* Vraw = (float*)Bs;        // [4][64]
        float* Vloc = Vraw + 256;        // [4][64]
        const int sid = blockIdx.x;                // 0..31
        const int b = sid >> 4, h = (sid >> 1) & 7, jhalf = sid & 1;

        // 1) xcs[d] = sum over 128 row-block partials (fp32, deterministic)
        {
            const float* p = xcs_part + (size_t)b * 128 * 512 + 2 * t;
            float a0 = 0.f, a1 = 0.f, c0 = 0.f, c1 = 0.f;
#pragma unroll 4
            for (int blk = 0; blk < 128; blk += 2) {
                float2 u = *(const float2*)(p + (size_t)blk * 512);
                float2 v = *(const float2*)(p + (size_t)(blk + 1) * 512);
                a0 += u.x; a1 += u.y; c0 += v.x; c1 += v.y;
            }
            xcs[2 * t] = a0 + c0; xcs[2 * t + 1] = a1 + c1;
        }
        __syncthreads();

        // 2) raw V dots: wave tt<3 -> x row tt of batch; wave 3 -> colsum row
        const int tt = t >> 6, cl = t & 63;
        const int col = h * 64 + cl;
        const float* wv = Wv + (size_t)col * EMBED;
        float r = 0.f;
        if (tt < 3) {
            const u16* xr = A + ((size_t)b * NSEQ + tt) * EMBED;
#pragma unroll 8
            for (int d = 0; d < EMBED; d += 8) {
                ushort8 xv = *(const ushort8*)(xr + d);
                f32x4 w0 = *(const f32x4*)(wv + d);
                f32x4 w1 = *(const f32x4*)(wv + d + 4);
                r = fmaf(bf2f(xv[0]), w0[0], r);
                r = fmaf(bf2f(xv[1]), w0[1], r);
                r = fmaf(bf2f(xv[2]), w0[2], r);
                r = fmaf(bf2f(xv[3]), w0[3], r);
                r = fmaf(bf2f(xv[4]), w1[0], r);
                r = fmaf(bf2f(xv[5]), w1[1], r);
                r = fmaf(bf2f(xv[6]), w1[2], r);
                r = fmaf(bf2f(xv[7]), w1[3], r);
            }
        } else {
#pragma unroll 8
            for (int d = 0; d < EMBED; d += 4) {
                f32x4 w = *(const f32x4*)(wv + d);
                r = fmaf(xcs[d],     w[0], r);
                r = fmaf(xcs[d + 1], w[1], r);
                r = fmaf(xcs[d + 2], w[2], r);
                r = fmaf(xcs[d + 3], w[3], r);
            }
        }
        Vraw[tt * 64 + cl] = r;
        __syncthreads();
        // biased rows; tail = colsumV - (v0+v1+v2) = r3 - (r0+r1+r2) + 2045*bv
        const float bvc = bv[col];
        if (tt < 3) Vloc[tt * 64 + cl] = r + bvc;
        else        Vloc[192 + cl] = r - (Vraw[cl] + Vraw[64 + cl] + Vraw[128 + cl])
                                       + 2045.f * bvc;
        __syncthreads();

        // 3) WT[b][j][4h+t] = sum_{c in head h} Vloc[t][c] * Wo[j][c]
        const int j = jhalf * 256 + t;
        const float* wo = Wo + (size_t)j * EMBED + h * 64;
        float a0 = 0.f, a1 = 0.f, a2 = 0.f, a3 = 0.f;
#pragma unroll
        for (int c = 0; c < 64; c += 4) {
            f32x4 w = *(const f32x4*)(wo + c);
#pragma unroll
            for (int z = 0; z < 4; ++z) {
                a0 = fmaf(Vloc[c + z],       w[z], a0);
                a1 = fmaf(Vloc[64 + c + z],  w[z], a1);
                a2 = fmaf(Vloc[128 + c + z], w[z], a2);
                a3 = fmaf(Vloc[192 + c + z], w[z], a3);
            }
        }
        float* wt = WT + ((size_t)b * 512 + j) * 32 + h * 4;
        wt[0] = a0; wt[1] = a1; wt[2] = a2; wt[3] = a3;
        return;
    }

    // ---------------- big GEMM blocks (Q|K only) ----------------
    const int bb = blockIdx.x - 32;
    const int m0 = (bb & 31) * 128;
    const int n0 = (bb >> 5) * 64;                     // 0..960
    const int sel = n0 >> 9;                           // 0:Q 1:K
    const float* bias = ((sel == 0) ? bq : bk) + (n0 & 511);

    const int wave = t >> 6, lane = t & 63;
    const int wm   = wave >> 1, wn = wave & 1;
    const int qd   = lane >> 4, lr = lane & 15;

    const int sr8 = lane >> 3;                 // row-in-8 for staging
    const int sg  = (lane & 7) ^ sr8;          // swizzled global granule
    const int soff = sg * 8;                   // global k offset (elems)

    f32x4 acc[4][2] = {};

    const u16* Asrc = A + (size_t)m0 * EMBED + (size_t)(wave * 8 + sr8) * EMBED + soff;
    const u16* Bsrc = W + (size_t)n0 * EMBED + (size_t)(wave * 8 + sr8) * EMBED + soff;

    u16* Ad0 = As + (size_t)(wave * 8) * 64;
    u16* Bd0 = Bs + (size_t)(wave * 8) * 64;

#define STAGE(bufi, kc)                                                          \
    do {                                                                         \
        u16* Ad = Ad0 + (bufi) * (128 * 64);                                     \
        u16* Bd = Bd0 + (bufi) * (64 * 64);                                      \
        _Pragma("unroll")                                                        \
        for (int j = 0; j < 4; ++j)                                              \
            __builtin_amdgcn_global_load_lds(                                    \
                (const __attribute__((address_space(1))) void*)(Asrc + (kc) + (size_t)j * 32 * EMBED), \
                (__attribute__((address_space(3))) void*)(Ad + j * 32 * 64), 16, 0, 0); \
        _Pragma("unroll")                                                        \
        for (int j = 0; j < 2; ++j)                                              \
            __builtin_amdgcn_global_load_lds(                                    \
                (const __attribute__((address_space(1))) void*)(Bsrc + (kc) + (size_t)j * 32 * EMBED), \
                (__attribute__((address_space(3))) void*)(Bd + j * 32 * 64), 16, 0, 0); \
    } while (0)

    STAGE(0, 0);
    __syncthreads();          // drains vmcnt(0): buffer 0 ready

    int cur = 0;
#pragma unroll
    for (int ki = 0; ki < 8; ++ki) {
        if (ki < 7) STAGE(cur ^ 1, (ki + 1) * 64);   // prefetch next K-step

        const u16* Ab = As + cur * (128 * 64);
        const u16* Bb = Bs + cur * (64 * 64);
#pragma unroll
        for (int kk = 0; kk < 2; ++kk) {
            const int gr = ((kk * 4 + qd) ^ (lr & 7)) * 8;
            bf16x8 af[4], bfr[2];
#pragma unroll
            for (int i = 0; i < 4; ++i)
                af[i]  = *(const bf16x8*)&Ab[(wm * 64 + i * 16 + lr) * 64 + gr];
#pragma unroll
            for (int i = 0; i < 2; ++i)
                bfr[i] = *(const bf16x8*)&Bb[(wn * 32 + i * 16 + lr) * 64 + gr];
#pragma unroll
            for (int mi = 0; mi < 4; ++mi)
#pragma unroll
                for (int ni = 0; ni < 2; ++ni)
                    acc[mi][ni] = __builtin_amdgcn_mfma_f32_16x16x32_bf16(
                        af[mi], bfr[ni], acc[mi][ni], 0, 0, 0);
        }
        if (ki < 7) __syncthreads();  // drains the prefetch; next buffer ready
        cur ^= 1;
    }
#undef STAGE

    // C/D layout: col=lane&15, row=(lane>>4)*4+reg
#pragma unroll
    for (int ni = 0; ni < 2; ++ni) {
        const int cl = wn * 32 + ni * 16 + lr;
        const float bb2 = bias[cl];
#pragma unroll
        for (int mi = 0; mi < 4; ++mi)
#pragma unroll
            for (int e = 0; e < 4; ++e) {
                const int row = m0 + wm * 64 + mi * 16 + qd * 4 + e;
                QKb[(size_t)row * 1024 + n0 + cl] = f2bf(acc[mi][ni][e] + bb2);
            }
    }
}

// ---------------------------------------------------------------------------
// Fused attention + K=32 output GEMM. 256 blocks x 16 rows (round-0 proven).
// ---------------------------------------------------------------------------
__global__ __launch_bounds__(256) void attn_out_kernel(
    const u16* __restrict__ QKb, const float* __restrict__ WT,
    const float* __restrict__ bo, float* __restrict__ out)
{
    __shared__ float E[16][32];
    const int r0   = blockIdx.x * 16;
    const int b    = r0 >> 11;
    const int wave = threadIdx.x >> 6, lane = threadIdx.x & 63;
    const int d0   = lane * 8;

#pragma unroll
    for (int i = 0; i < 4; ++i) {
        const int rl = wave * 4 + i;
        const int r  = r0 + rl;
        const int sr = r & (NSEQ - 1);
        const u16* Qr = QKb + (size_t)r * 1024 + d0;
        const u16* Kr = QKb + (size_t)r * 1024 + 512 + d0;

        ushort8 qv = *(const ushort8*)Qr;
        ushort8 kv = *(const ushort8*)Kr;
        float q[8], k[8];
#pragma unroll
        for (int z = 0; z < 8; ++z) { q[z] = bf2f(qv[z]); k[z] = bf2f(kv[z]); }

        float s1 = 0.f;
#pragma unroll
        for (int z = 0; z < 8; ++z) s1 = fmaf(q[z], k[z], s1);

        float s0 = 0.f, s2 = 0.f;
        if (sr > 0) {
            ushort8 pv = *(const ushort8*)(Kr - 1024);
#pragma unroll
            for (int z = 0; z < 8; ++z) s0 = fmaf(q[z], bf2f(pv[z]), s0);
        }
        if (sr < NSEQ - 1) {
            ushort8 nv = *(const ushort8*)(Kr + 1024);
#pragma unroll
            for (int z = 0; z < 8; ++z) s2 = fmaf(q[z], bf2f(nv[z]), s2);
        }
#pragma unroll
        for (int off = 1; off <= 4; off <<= 1) {
            s0 += __shfl_xor(s0, off);
            s1 += __shfl_xor(s1, off);
            s2 += __shfl_xor(s2, off);
        }
        const float m  = fmaxf(fmaxf(s0, s1), fmaxf(s2, 0.f));
        const float e0 = __expf(s0 - m);
        const float e1 = __expf(s1 - m);
        const float e2 = __expf(s2 - m);
        const float eb = __expf(-m);
        const float rd = 1.f / (e0 + e1 + e2 + (float)(NSEQ - 3) * eb);
        const int h = lane >> 3, jj = lane & 7;
        const float coef = (jj == 0) ? e0 : (jj == 1) ? e1 : (jj == 2) ? e2 : eb;
        if (jj < 4) E[rl][h * 4 + jj] = coef * rd;
    }
    __syncthreads();

    const int j0 = threadIdx.x * 2;
    const float* WTb = WT + (size_t)b * 512 * 32;
    float w0[32], w1[32];
#pragma unroll
    for (int s = 0; s < 32; ++s) {
        w0[s] = WTb[(size_t)j0 * 32 + s];
        w1[s] = WTb[(size_t)(j0 + 1) * 32 + s];
    }
    const float b0 = bo[j0], b1 = bo[j0 + 1];
#pragma unroll
    for (int rl = 0; rl < 16; ++rl) {
        float a0 = b0, a1 = b1;
#pragma unroll
        for (int s = 0; s < 32; ++s) {
            const float e = E[rl][s];
            a0 = fmaf(e, w0[s], a0);
            a1 = fmaf(e, w1[s], a1);
        }
        *(float2*)(out + (size_t)(r0 + rl) * EMBED + j0) = make_float2(a0, a1);
    }
}

extern "C" void kernel_launch(void* const* d_in, const int* in_sizes, int n_in,
                              void* d_out, int out_size, void* d_ws, size_t ws_size,
                              hipStream_t stream)
{
    const float* x  = (const float*)d_in[0];
    const float* Wq = (const float*)d_in[1];
    const float* bq = (const float*)d_in[2];
    const float* Wk = (const float*)d_in[3];
    const float* bk = (const float*)d_in[4];
    const float* Wv = (const float*)d_in[5];
    const float* bv = (const float*)d_in[6];
    const float* Wo = (const float*)d_in[7];
    const float* bo = (const float*)d_in[8];
    float* out = (float*)d_out;

    u16*   QKb      = (u16*)d_ws;                      // 4096*1024 u16 (Q|K bf16)
    u16*   xb       = QKb + (size_t)NROWS * 1024;      // 4096*512 bf16
    u16*   Wcat     = xb + XELEMS;                     // 1024*512 bf16 (Wq|Wk)
    float* xcs_part = (float*)(Wcat + WQKELEMS);       // 2*128*512 f32
    float* WT       = xcs_part + 2 * 128 * 512;        // 2*512*32 f32

    prep_kernel<<<512, 256, 0, stream>>>(x, Wq, Wk, xb, Wcat, xcs_part);
    gemm_qk_mfma<<<544, 256, 0, stream>>>(xb, Wcat, bq, bk, xcs_part, bv, Wv, Wo,
                                          QKb, WT);
    attn_out_kernel<<<256, 256, 0, stream>>>(QKb, WT, bo, out);
}

// Round 4
// 115.973 us; speedup vs baseline: 1.0870x; 1.0140x over previous
//
#include <hip/hip_runtime.h>
#include <hip/hip_bf16.h>

#define EMBED 512
#define NSEQ 2048
#define NROWS 4096

typedef unsigned short u16;
typedef __bf16 bf16x8 __attribute__((ext_vector_type(8)));
typedef float f32x4 __attribute__((ext_vector_type(4)));
typedef unsigned short ushort8 __attribute__((ext_vector_type(8)));

__device__ __forceinline__ u16 f2bf(float f) {
    unsigned u = __float_as_uint(f);
    unsigned r = (u + 0x7FFFu + ((u >> 16) & 1u)) >> 16;
    return (u16)r;
}
__device__ __forceinline__ float bf2f(u16 v) {
    return __uint_as_float((unsigned)v << 16);
}

#define XELEMS    (NROWS * EMBED)     // 2097152
#define WQKELEMS  (1024 * EMBED)      // 524288

// ---------------------------------------------------------------------------
// prep: blocks 0..255: x -> bf16 (16 rows each) + per-block fp32 column sums
//       blocks 256..511: Wq|Wk -> Wcat bf16.
// xcs_part layout: [batch][blk][dim] — coalesced write here, coalesced
// float2 read in the small reduce blocks.
// ---------------------------------------------------------------------------
__global__ __launch_bounds__(256) void prep_kernel(
    const float* __restrict__ x,
    const float* __restrict__ Wq, const float* __restrict__ Wk,
    u16* __restrict__ xb, u16* __restrict__ Wcat,
    float* __restrict__ xcs_part)
{
    __shared__ float cs[4][512];
    const int bid = blockIdx.x, t = threadIdx.x;
    if (bid < 256) {
        const float* src = x + (size_t)bid * 16 * EMBED;
        u16* dst = xb + (size_t)bid * 16 * EMBED;
        const int rl = t >> 6;            // row-in-4 (== wave)
        const int co = (t & 63) * 8;      // col octet
        float s0=0.f,s1=0.f,s2=0.f,s3=0.f,s4=0.f,s5=0.f,s6=0.f,s7=0.f;
#pragma unroll
        for (int i = 0; i < 4; ++i) {
            const size_t off = (size_t)(i * 4 + rl) * EMBED + co;
            float4 a = *(const float4*)(src + off);
            float4 b = *(const float4*)(src + off + 4);
            union { u16 u[8]; uint4 v; } p;
            p.u[0]=f2bf(a.x); p.u[1]=f2bf(a.y); p.u[2]=f2bf(a.z); p.u[3]=f2bf(a.w);
            p.u[4]=f2bf(b.x); p.u[5]=f2bf(b.y); p.u[6]=f2bf(b.z); p.u[7]=f2bf(b.w);
            *(uint4*)(dst + off) = p.v;
            s0+=a.x; s1+=a.y; s2+=a.z; s3+=a.w;
            s4+=b.x; s5+=b.y; s6+=b.z; s7+=b.w;
        }
        f32x4 v0 = {s0,s1,s2,s3}, v1 = {s4,s5,s6,s7};
        *(f32x4*)&cs[rl][co]     = v0;
        *(f32x4*)&cs[rl][co + 4] = v1;
        __syncthreads();
        const int b = bid >> 7, blk = bid & 127;
#pragma unroll
        for (int d = t; d < 512; d += 256) {
            xcs_part[((size_t)b * 128 + blk) * 512 + d] =
                cs[0][d] + cs[1][d] + cs[2][d] + cs[3][d];
        }
    } else {
        const long long e0 = (long long)(bid - 256) * 2048 + (long long)t * 8;
        const int row = (int)(e0 >> 9), col = (int)(e0 & 511);
        const float* src = (row < 512) ? (Wq + (size_t)row * EMBED + col)
                                       : (Wk + (size_t)(row - 512) * EMBED + col);
        float4 a = *(const float4*)(src);
        float4 b = *(const float4*)(src + 4);
        union { u16 u[8]; uint4 v; } p;
        p.u[0]=f2bf(a.x); p.u[1]=f2bf(a.y); p.u[2]=f2bf(a.z); p.u[3]=f2bf(a.w);
        p.u[4]=f2bf(b.x); p.u[5]=f2bf(b.y); p.u[6]=f2bf(b.z); p.u[7]=f2bf(b.w);
        *(uint4*)(Wcat + e0) = p.v;
    }
}

// ---------------------------------------------------------------------------
// blocks 0..31:   small V/WT epilogue blocks (run first, overlap the GEMM).
// blocks 32..1055: Q|K GEMM, 64x64 tiles, BK=64, single-buffered 16 KB LDS.
// Small tile -> ~60 VGPR, 16 KB LDS -> up to 8 resident blocks/CU: latency
// hiding comes from cross-block overlap (m114), not intra-block pipelining.
// ---------------------------------------------------------------------------
__global__ __launch_bounds__(256) void gemm_qk_mfma(
    const u16* __restrict__ A, const u16* __restrict__ W,
    const float* __restrict__ bq, const float* __restrict__ bk,
    const float* __restrict__ xcs_part, const float* __restrict__ bv,
    const float* __restrict__ Wv, const float* __restrict__ Wo,
    u16* __restrict__ QKb, float* __restrict__ WT)
{
    __shared__ __align__(16) u16 As[64 * 64];   // 8 KB
    __shared__ __align__(16) u16 Bs[64 * 64];   // 8 KB
    const int t = threadIdx.x;

    if (blockIdx.x < 32) {
        // ---------------- small epilogue blocks ----------------
        float* xcs  = (float*)As;        // [512]
        float* Vraw = (float*)Bs;        // [4][64]
        float* Vloc = Vraw + 256;        // [4][64]
        const int sid = blockIdx.x;                // 0..31
        const int b = sid >> 4, h = (sid >> 1) & 7, jhalf = sid & 1;

        // 1) xcs[d] = sum over 128 row-block partials (fp32, deterministic)
        {
            const float* p = xcs_part + (size_t)b * 128 * 512 + 2 * t;
            float a0 = 0.f, a1 = 0.f, c0 = 0.f, c1 = 0.f;
#pragma unroll 4
            for (int blk = 0; blk < 128; blk += 2) {
                float2 u = *(const float2*)(p + (size_t)blk * 512);
                float2 v = *(const float2*)(p + (size_t)(blk + 1) * 512);
                a0 += u.x; a1 += u.y; c0 += v.x; c1 += v.y;
            }
            xcs[2 * t] = a0 + c0; xcs[2 * t + 1] = a1 + c1;
        }
        __syncthreads();

        // 2) raw V dots: wave tt<3 -> x row tt of batch; wave 3 -> colsum row
        const int tt = t >> 6, cl = t & 63;
        const int col = h * 64 + cl;
        const float* wv = Wv + (size_t)col * EMBED;
        float r = 0.f;
        if (tt < 3) {
            const u16* xr = A + ((size_t)b * NSEQ + tt) * EMBED;
#pragma unroll 8
            for (int d = 0; d < EMBED; d += 8) {
                ushort8 xv = *(const ushort8*)(xr + d);
                f32x4 w0 = *(const f32x4*)(wv + d);
                f32x4 w1 = *(const f32x4*)(wv + d + 4);
                r = fmaf(bf2f(xv[0]), w0[0], r);
                r = fmaf(bf2f(xv[1]), w0[1], r);
                r = fmaf(bf2f(xv[2]), w0[2], r);
                r = fmaf(bf2f(xv[3]), w0[3], r);
                r = fmaf(bf2f(xv[4]), w1[0], r);
                r = fmaf(bf2f(xv[5]), w1[1], r);
                r = fmaf(bf2f(xv[6]), w1[2], r);
                r = fmaf(bf2f(xv[7]), w1[3], r);
            }
        } else {
#pragma unroll 8
            for (int d = 0; d < EMBED; d += 4) {
                f32x4 w = *(const f32x4*)(wv + d);
                r = fmaf(xcs[d],     w[0], r);
                r = fmaf(xcs[d + 1], w[1], r);
                r = fmaf(xcs[d + 2], w[2], r);
                r = fmaf(xcs[d + 3], w[3], r);
            }
        }
        Vraw[tt * 64 + cl] = r;
        __syncthreads();
        // biased rows; tail = colsumV - (v0+v1+v2) = r3 - (r0+r1+r2) + 2045*bv
        const float bvc = bv[col];
        if (tt < 3) Vloc[tt * 64 + cl] = r + bvc;
        else        Vloc[192 + cl] = r - (Vraw[cl] + Vraw[64 + cl] + Vraw[128 + cl])
                                       + 2045.f * bvc;
        __syncthreads();

        // 3) WT[b][j][4h+t] = sum_{c in head h} Vloc[t][c] * Wo[j][c]
        const int j = jhalf * 256 + t;
        const float* wo = Wo + (size_t)j * EMBED + h * 64;
        float a0 = 0.f, a1 = 0.f, a2 = 0.f, a3 = 0.f;
#pragma unroll
        for (int c = 0; c < 64; c += 4) {
            f32x4 w = *(const f32x4*)(wo + c);
#pragma unroll
            for (int z = 0; z < 4; ++z) {
                a0 = fmaf(Vloc[c + z],       w[z], a0);
                a1 = fmaf(Vloc[64 + c + z],  w[z], a1);
                a2 = fmaf(Vloc[128 + c + z], w[z], a2);
                a3 = fmaf(Vloc[192 + c + z], w[z], a3);
            }
        }
        float* wt = WT + ((size_t)b * 512 + j) * 32 + h * 4;
        wt[0] = a0; wt[1] = a1; wt[2] = a2; wt[3] = a3;
        return;
    }

    // ---------------- big GEMM blocks (Q|K only), 64x64 tile ----------------
    const int bb = blockIdx.x - 32;
    const int m0 = (bb & 63) * 64;
    const int n0 = (bb >> 6) * 64;                     // 0..960
    const int sel = n0 >> 9;                           // 0:Q 1:K
    const float* bias = ((sel == 0) ? bq : bk) + (n0 & 511);

    const int wave = t >> 6, lane = t & 63;
    const int wm   = wave >> 1, wn = wave & 1;
    const int qd   = lane >> 4, lr = lane & 15;

    const int sr8 = lane >> 3;                 // row-in-8 for staging
    const int sg  = (lane & 7) ^ sr8;          // swizzled global granule
    const int soff = sg * 8;                   // global k offset (elems)

    f32x4 acc[2][2] = {};

    const u16* Asrc = A + ((size_t)m0 + wave * 8 + sr8) * EMBED + soff;
    const u16* Bsrc = W + ((size_t)n0 + wave * 8 + sr8) * EMBED + soff;
    u16* Adst = As + (size_t)(wave * 8) * 64;
    u16* Bdst = Bs + (size_t)(wave * 8) * 64;

    for (int kc = 0; kc < EMBED; kc += 64) {
#pragma unroll
        for (int j = 0; j < 2; ++j) {
            __builtin_amdgcn_global_load_lds(
                (const __attribute__((address_space(1))) void*)(Asrc + kc + (size_t)j * 32 * EMBED),
                (__attribute__((address_space(3))) void*)(Adst + j * 32 * 64), 16, 0, 0);
            __builtin_amdgcn_global_load_lds(
                (const __attribute__((address_space(1))) void*)(Bsrc + kc + (size_t)j * 32 * EMBED),
                (__attribute__((address_space(3))) void*)(Bdst + j * 32 * 64), 16, 0, 0);
        }
        __syncthreads();

#pragma unroll
        for (int kk = 0; kk < 2; ++kk) {
            const int gr = ((kk * 4 + qd) ^ (lr & 7)) * 8;
            bf16x8 af[2], bfr[2];
#pragma unroll
            for (int i = 0; i < 2; ++i)
                af[i]  = *(const bf16x8*)&As[(wm * 32 + i * 16 + lr) * 64 + gr];
#pragma unroll
            for (int i = 0; i < 2; ++i)
                bfr[i] = *(const bf16x8*)&Bs[(wn * 32 + i * 16 + lr) * 64 + gr];
#pragma unroll
            for (int mi = 0; mi < 2; ++mi)
#pragma unroll
                for (int ni = 0; ni < 2; ++ni)
                    acc[mi][ni] = __builtin_amdgcn_mfma_f32_16x16x32_bf16(
                        af[mi], bfr[ni], acc[mi][ni], 0, 0, 0);
        }
        __syncthreads();
    }

    // C/D layout: col=lane&15, row=(lane>>4)*4+reg
#pragma unroll
    for (int ni = 0; ni < 2; ++ni) {
        const int cl = wn * 32 + ni * 16 + lr;
        const float bb2 = bias[cl];
#pragma unroll
        for (int mi = 0; mi < 2; ++mi)
#pragma unroll
            for (int e = 0; e < 4; ++e) {
                const int row = m0 + wm * 32 + mi * 16 + qd * 4 + e;
                QKb[(size_t)row * 1024 + n0 + cl] = f2bf(acc[mi][ni][e] + bb2);
            }
    }
}

// ---------------------------------------------------------------------------
// Fused attention + K=32 output GEMM. 256 blocks x 16 rows (round-0 proven).
// ---------------------------------------------------------------------------
__global__ __launch_bounds__(256) void attn_out_kernel(
    const u16* __restrict__ QKb, const float* __restrict__ WT,
    const float* __restrict__ bo, float* __restrict__ out)
{
    __shared__ float E[16][32];
    const int r0   = blockIdx.x * 16;
    const int b    = r0 >> 11;
    const int wave = threadIdx.x >> 6, lane = threadIdx.x & 63;
    const int d0   = lane * 8;

#pragma unroll
    for (int i = 0; i < 4; ++i) {
        const int rl = wave * 4 + i;
        const int r  = r0 + rl;
        const int sr = r & (NSEQ - 1);
        const u16* Qr = QKb + (size_t)r * 1024 + d0;
        const u16* Kr = QKb + (size_t)r * 1024 + 512 + d0;

        ushort8 qv = *(const ushort8*)Qr;
        ushort8 kv = *(const ushort8*)Kr;
        float q[8], k[8];
#pragma unroll
        for (int z = 0; z < 8; ++z) { q[z] = bf2f(qv[z]); k[z] = bf2f(kv[z]); }

        float s1 = 0.f;
#pragma unroll
        for (int z = 0; z < 8; ++z) s1 = fmaf(q[z], k[z], s1);

        float s0 = 0.f, s2 = 0.f;
        if (sr > 0) {
            ushort8 pv = *(const ushort8*)(Kr - 1024);
#pragma unroll
            for (int z = 0; z < 8; ++z) s0 = fmaf(q[z], bf2f(pv[z]), s0);
        }
        if (sr < NSEQ - 1) {
            ushort8 nv = *(const ushort8*)(Kr + 1024);
#pragma unroll
            for (int z = 0; z < 8; ++z) s2 = fmaf(q[z], bf2f(nv[z]), s2);
        }
#pragma unroll
        for (int off = 1; off <= 4; off <<= 1) {
            s0 += __shfl_xor(s0, off);
            s1 += __shfl_xor(s1, off);
            s2 += __shfl_xor(s2, off);
        }
        const float m  = fmaxf(fmaxf(s0, s1), fmaxf(s2, 0.f));
        const float e0 = __expf(s0 - m);
        const float e1 = __expf(s1 - m);
        const float e2 = __expf(s2 - m);
        const float eb = __expf(-m);
        const float rd = 1.f / (e0 + e1 + e2 + (float)(NSEQ - 3) * eb);
        const int h = lane >> 3, jj = lane & 7;
        const float coef = (jj == 0) ? e0 : (jj == 1) ? e1 : (jj == 2) ? e2 : eb;
        if (jj < 4) E[rl][h * 4 + jj] = coef * rd;
    }
    __syncthreads();

    const int j0 = threadIdx.x * 2;
    const float* WTb = WT + (size_t)b * 512 * 32;
    float w0[32], w1[32];
#pragma unroll
    for (int s = 0; s < 32; ++s) {
        w0[s] = WTb[(size_t)j0 * 32 + s];
        w1[s] = WTb[(size_t)(j0 + 1) * 32 + s];
    }
    const float b0 = bo[j0], b1 = bo[j0 + 1];
#pragma unroll
    for (int rl = 0; rl < 16; ++rl) {
        float a0 = b0, a1 = b1;
#pragma unroll
        for (int s = 0; s < 32; ++s) {
            const float e = E[rl][s];
            a0 = fmaf(e, w0[s], a0);
            a1 = fmaf(e, w1[s], a1);
        }
        *(float2*)(out + (size_t)(r0 + rl) * EMBED + j0) = make_float2(a0, a1);
    }
}

extern "C" void kernel_launch(void* const* d_in, const int* in_sizes, int n_in,
                              void* d_out, int out_size, void* d_ws, size_t ws_size,
                              hipStream_t stream)
{
    const float* x  = (const float*)d_in[0];
    const float* Wq = (const float*)d_in[1];
    const float* bq = (const float*)d_in[2];
    const float* Wk = (const float*)d_in[3];
    const float* bk = (const float*)d_in[4];
    const float* Wv = (const float*)d_in[5];
    const float* bv = (const float*)d_in[6];
    const float* Wo = (const float*)d_in[7];
    const float* bo = (const float*)d_in[8];
    float* out = (float*)d_out;

    u16*   QKb      = (u16*)d_ws;                      // 4096*1024 u16 (Q|K bf16)
    u16*   xb       = QKb + (size_t)NROWS * 1024;      // 4096*512 bf16
    u16*   Wcat     = xb + XELEMS;                     // 1024*512 bf16 (Wq|Wk)
    float* xcs_part = (float*)(Wcat + WQKELEMS);       // 2*128*512 f32
    float* WT       = xcs_part + 2 * 128 * 512;        // 2*512*32 f32

    prep_kernel<<<512, 256, 0, stream>>>(x, Wq, Wk, xb, Wcat, xcs_part);
    gemm_qk_mfma<<<1056, 256, 0, stream>>>(xb, Wcat, bq, bk, xcs_part, bv, Wv, Wo,
                                           QKb, WT);
    attn_out_kernel<<<256, 256, 0, stream>>>(QKb, WT, bo, out);
}